// Round 5
// baseline (97.674 us; speedup 1.0000x reference)
//
#include <hip/hip_runtime.h>
#include <hip/hip_bf16.h>

// InnerProductFeatures: V=131072, C=64, D=8
//   xr[v,d,c] = x[v, d*64 + c]
//   s[v,k]    = sum_{d,c} xr[v,d,c] * W[c,k,d]     (W flat: c*64 + k*8 + d)
//   xOx[v,i]  = sum_k s[v,k] * xr[v,k,i]
//   out       = tanh(xOx)   shape (V, 64) fp32
//
// One wave per row. Lane l: d0 = l>>4 (16-lane "row"), c0 = (l&15)*4.
//   f32x4 a = xr[v, d0,   c0..c0+3] = x4[v*128 + l]        (1 KiB wave load)
//   f32x4 b = xr[v, d0+4, c0..c0+3] = x4[v*128 + 64 + l]   (1 KiB wave load)
//
// R4 fix: __builtin_nontemporal_load needs a NATIVE vector type
// (ext_vector_type), not HIP_vector_type<float,4>. Math network unchanged
// (verified, absmax 4e-3). Depth-2 software pipeline (4 KiB/wave in flight)
// + nontemporal x loads / out stores (read-once / write-once streams).

typedef float f32x4 __attribute__((ext_vector_type(4)));

__device__ __forceinline__ float fast_tanh(float x) {
    float e = __expf(2.0f * x);
    return 1.0f - 2.0f / (e + 1.0f);
}

// fold16(a,b): even 16-rows get a[l]+a[l^16]; odd rows get b[l]+b[l^16].
__device__ __forceinline__ float fold16(float a, float b, int lane) {
    float x   = (lane & 16) ? a : b;
    float sh  = __shfl_xor(x, 16, 64);
    float own = (lane & 16) ? b : a;
    return own + sh;
}

// fold32(a,b): lanes<32 get a[l]+a[l+32]; lanes>=32 get b[l-32]+b[l].
__device__ __forceinline__ float fold32(float a, float b, int lane) {
    float x   = (lane & 32) ? a : b;
    float sh  = __shfl_xor(x, 32, 64);
    float own = (lane & 32) ? b : a;
    return own + sh;
}

// v + dpp(v): 0xB1 = quad xor1, 0x4E = quad xor2,
// 0x141 = row_half_mirror (xor4 once quad-uniform),
// 0x140 = row_mirror (xor8 once 8-uniform).
template <int CTRL>
__device__ __forceinline__ float dpp_add(float v) {
    int i = __builtin_bit_cast(int, v);
    int p = __builtin_amdgcn_update_dpp(i, i, CTRL, 0xF, 0xF, false);
    return v + __builtin_bit_cast(float, p);
}

// Full within-16-lane sum (row-uniform result). VALU-only.
__device__ __forceinline__ float row16_sum(float v) {
    v = dpp_add<0xB1>(v);   // xor1
    v = dpp_add<0x4E>(v);   // xor2
    v = dpp_add<0x141>(v);  // xor4
    v = dpp_add<0x140>(v);  // xor8
    return v;
}

__global__ __launch_bounds__(256, 4)
void ipf_kernel(const float* __restrict__ x, const float* __restrict__ W,
                float* __restrict__ out, int V) {
    const int tid  = blockIdx.x * blockDim.x + threadIdx.x;
    const int lane = threadIdx.x & 63;
    const int wave = tid >> 6;
    const int nwav = (gridDim.x * blockDim.x) >> 6;

    const int d0 = lane >> 4;         // 0..3
    const int c0 = (lane & 15) << 2;  // 0,4,...,60

    // W fragments in registers: Wa[j][k] = W[c0+j, k, d0], Wb = at d0+4.
    float Wa[4][8], Wb[4][8];
#pragma unroll
    for (int j = 0; j < 4; ++j) {
        const float* wp = W + (size_t)(c0 + j) * 64 + d0;
#pragma unroll
        for (int k = 0; k < 8; ++k) {
            Wa[j][k] = wp[k * 8];
            Wb[j][k] = wp[k * 8 + 4];
        }
    }

    const f32x4* __restrict__ x4 = reinterpret_cast<const f32x4*>(x);

    // Depth-2 pipeline: rows v0 (compute), v1 (in flight), v2 (issue now).
    int v0 = wave;
    if (v0 >= V) return;
    f32x4 a0 = __builtin_nontemporal_load(x4 + (size_t)v0 * 128 + lane);
    f32x4 b0 = __builtin_nontemporal_load(x4 + (size_t)v0 * 128 + 64 + lane);
    int v1 = v0 + nwav;
    f32x4 a1 = {}, b1 = {};
    if (v1 < V) {
        a1 = __builtin_nontemporal_load(x4 + (size_t)v1 * 128 + lane);
        b1 = __builtin_nontemporal_load(x4 + (size_t)v1 * 128 + 64 + lane);
    }

    while (true) {
        const int v2 = v1 + nwav;
        f32x4 a2 = {}, b2 = {};
        if (v2 < V) {  // issue row v0+2*nwav now; used two iterations later
            a2 = __builtin_nontemporal_load(x4 + (size_t)v2 * 128 + lane);
            b2 = __builtin_nontemporal_load(x4 + (size_t)v2 * 128 + 64 + lane);
        }

        const float xa[4] = {a0.x, a0.y, a0.z, a0.w};
        const float xb[4] = {b0.x, b0.y, b0.z, b0.w};

        // Stage 1 partials: p[k] = sum_j xa[j]*Wa[j][k] + xb[j]*Wb[j][k]
        float p[8];
#pragma unroll
        for (int k = 0; k < 8; ++k) {
            float acc = 0.0f;
#pragma unroll
            for (int j = 0; j < 4; ++j) {
                acc = fmaf(xa[j], Wa[j][k], acc);
                acc = fmaf(xb[j], Wb[j][k], acc);
            }
            p[k] = acc;
        }

        // Within-row sums (DPP, VALU pipe): row-uniform R_r[k].
#pragma unroll
        for (int k = 0; k < 8; ++k) p[k] = row16_sum(p[k]);

        // Cross-row folds (6 shfl): u = s[d0], w = s[d0+4].
        float t0 = fold16(p[0], p[1], lane);
        float t1 = fold16(p[2], p[3], lane);
        float t2 = fold16(p[4], p[5], lane);
        float t3 = fold16(p[6], p[7], lane);
        float u  = fold32(t0, t1, lane);
        float w  = fold32(t2, t3, lane);

        // Stage 2: contribution to column c0+j from rows d0 and d0+4.
        float q0 = fmaf(u, xa[0], w * xb[0]);
        float q1 = fmaf(u, xa[1], w * xb[1]);
        float q2 = fmaf(u, xa[2], w * xb[2]);
        float q3 = fmaf(u, xa[3], w * xb[3]);

        // Reduce q over the 4 d0-groups (3 shfl); one column per lane.
        float A = fold16(q0, q1, lane);
        float B = fold16(q2, q3, lane);
        float r = fold32(A, B, lane);

        const int col = ((lane & 15) << 2) + d0;
        __builtin_nontemporal_store(fast_tanh(r), out + (size_t)v0 * 64 + col);

        if (v1 >= V) break;
        v0 = v1; v1 = v2;
        a0 = a1; b0 = b1;
        a1 = a2; b1 = b2;
    }
}

extern "C" void kernel_launch(void* const* d_in, const int* in_sizes, int n_in,
                              void* d_out, int out_size, void* d_ws, size_t ws_size,
                              hipStream_t stream) {
    const float* x = (const float*)d_in[0];
    const float* W = (const float*)d_in[1];
    float* out = (float*)d_out;
    const int V = in_sizes[0] / 512;  // C*D = 512 floats per row

    const int block = 256;
    const int grid  = 2048;  // 8192 waves, 16 rows each
    ipf_kernel<<<grid, block, 0, stream>>>(x, W, out, V);
}

// Round 6
// 95.755 us; speedup vs baseline: 1.0200x; 1.0200x over previous
//
#include <hip/hip_runtime.h>

// InnerProductFeatures: V=131072, C=64, D=8
//   xr[v,d,c] = x[v, d*64 + c]
//   s[v,k]    = sum_{d,c} xr[v,d,c] * W[c,k,d]     (W flat: c*64 + k*8 + d)
//   xOx[v,i]  = sum_k s[v,k] * xr[v,k,i]
//   out       = tanh(xOx)   shape (V, 64) fp32
//
// One wave per row; lane l: d0 = l>>4 (16-lane "row"), c0 = (l&15)*4.
//   a = xr[v, d0,   c0..c0+3] = x4[v*128 + l]        (1 KiB wave load)
//   b = xr[v, d0+4, c0..c0+3] = x4[v*128 + 64 + l]   (1 KiB wave load)
//
// R6 changes vs R3 (92.2us):
//  * TWO independent rows per loop iteration (straight-line) — doubles the
//    number of independent dependency chains per wave; per-row serial chain
//    (vmcnt -> FMA tree -> DPP -> 3 shfl levels) was leaving SIMDs ~80% idle.
//  * Reduction reordered by linearity: cross-row shfl folds FIRST on raw
//    partials, within-row DPP sums AFTER on just u,w: 32 DPP/row -> 8 DPP/row.
//  * Plain cached loads/stores (nontemporal regressed in R5: it defeats L3
//    residency of x across graph replays).

typedef float f32x4 __attribute__((ext_vector_type(4)));

__device__ __forceinline__ float fast_tanh(float x) {
    float e = __expf(2.0f * x);
    return 1.0f - 2.0f / (e + 1.0f);
}

// fold16(a,b): even 16-rows get a[l]+a[l^16]; odd rows get b[l]+b[l^16].
__device__ __forceinline__ float fold16(float a, float b, int lane) {
    float x   = (lane & 16) ? a : b;
    float sh  = __shfl_xor(x, 16, 64);
    float own = (lane & 16) ? b : a;
    return own + sh;
}

// fold32(a,b): lanes<32 get a[l]+a[l^32]; lanes>=32 get b[l]+b[l^32].
__device__ __forceinline__ float fold32(float a, float b, int lane) {
    float x   = (lane & 32) ? a : b;
    float sh  = __shfl_xor(x, 32, 64);
    float own = (lane & 32) ? b : a;
    return own + sh;
}

// v + dpp(v): 0xB1 quad xor1, 0x4E quad xor2, 0x141 row_half_mirror (xor4),
// 0x140 row_mirror (xor8).
template <int CTRL>
__device__ __forceinline__ float dpp_add(float v) {
    int i = __builtin_bit_cast(int, v);
    int p = __builtin_amdgcn_update_dpp(i, i, CTRL, 0xF, 0xF, false);
    return v + __builtin_bit_cast(float, p);
}

// Full within-16-lane sum (row-uniform result). VALU-only.
__device__ __forceinline__ float row16_sum(float v) {
    v = dpp_add<0xB1>(v);
    v = dpp_add<0x4E>(v);
    v = dpp_add<0x141>(v);
    v = dpp_add<0x140>(v);
    return v;
}

__global__ __launch_bounds__(256, 3)
void ipf_kernel(const float* __restrict__ x, const float* __restrict__ W,
                float* __restrict__ out, int V) {
    const int tid  = blockIdx.x * blockDim.x + threadIdx.x;
    const int lane = threadIdx.x & 63;
    const int wave = tid >> 6;
    const int nwav = (gridDim.x * blockDim.x) >> 6;

    const int d0 = lane >> 4;         // 0..3
    const int c0 = (lane & 15) << 2;  // 0,4,...,60

    // W fragments in registers: Wa[j][k] = W[c0+j, k, d0], Wb = at d0+4.
    float Wa[4][8], Wb[4][8];
#pragma unroll
    for (int j = 0; j < 4; ++j) {
        const float* wp = W + (size_t)(c0 + j) * 64 + d0;
#pragma unroll
        for (int k = 0; k < 8; ++k) {
            Wa[j][k] = wp[k * 8];
            Wb[j][k] = wp[k * 8 + 4];
        }
    }

    const f32x4* __restrict__ x4 = reinterpret_cast<const f32x4*>(x);

    // Full per-row pipeline: partials -> cross-row folds -> row sums ->
    // stage2 -> fold to one column/lane -> tanh -> store.
    auto process_row = [&](const f32x4& a, const f32x4& b, int v) {
        const float xa[4] = {a.x, a.y, a.z, a.w};
        const float xb[4] = {b.x, b.y, b.z, b.w};

        // p[k](lane) = this lane's partial of s[k]
        float p[8];
#pragma unroll
        for (int k = 0; k < 8; ++k) {
            float acc = 0.0f;
#pragma unroll
            for (int j = 0; j < 4; ++j) {
                acc = fmaf(xa[j], Wa[j][k], acc);
                acc = fmaf(xb[j], Wb[j][k], acc);
            }
            p[k] = acc;
        }

        // Cross-row folds FIRST (linearity: fold/rowsum commute).
        // t0: row0 holds p0 summed over rows{0,1}; row2: p0 over {2,3};
        //     rows 1,3 the same for p1. Analogously t1(p2,p3) etc.
        float t0 = fold16(p[0], p[1], lane);
        float t1 = fold16(p[2], p[3], lane);
        float t2 = fold16(p[4], p[5], lane);
        float t3 = fold16(p[6], p[7], lane);
        // fold32 completes the 4-row sum; row r now holds p_r (u) / p_{r+4} (w)
        // at each (l&15) position.
        float u = fold32(t0, t1, lane);
        float w = fold32(t2, t3, lane);
        // Sum the 16 positions: u = s[d0], w = s[d0+4], row-uniform.
        u = row16_sum(u);
        w = row16_sum(w);

        // Stage 2: contribution to column c0+j from rows d0 and d0+4.
        float q0 = fmaf(u, xa[0], w * xb[0]);
        float q1 = fmaf(u, xa[1], w * xb[1]);
        float q2 = fmaf(u, xa[2], w * xb[2]);
        float q3 = fmaf(u, xa[3], w * xb[3]);

        // Reduce q over the 4 same-(l&15) lanes; one column per lane.
        float A = fold16(q0, q1, lane);
        float B = fold16(q2, q3, lane);
        float r = fold32(A, B, lane);

        const int col = ((lane & 15) << 2) + d0;
        out[(size_t)v * 64 + col] = fast_tanh(r);
    };

    // Two rows per iteration, depth-1 pair prefetch, straight-line.
    // V = niter * 2 * nwav exactly (131072 = 8 * 2 * 8192).
    const int niter = V / (2 * nwav);
    int vA = wave;
    int vB = wave + nwav;
    if (vA >= V) return;

    f32x4 aA = x4[(size_t)vA * 128 + lane];
    f32x4 bA = x4[(size_t)vA * 128 + 64 + lane];
    f32x4 aB = x4[(size_t)vB * 128 + lane];
    f32x4 bB = x4[(size_t)vB * 128 + 64 + lane];

    for (int it = 0; it < niter; ++it) {
        // Prefetch next pair (wave-uniform clamp keeps loads unconditional
        // and in-bounds; last iteration's prefetch is discarded).
        int vA2 = vA + 2 * nwav; vA2 = (vA2 < V) ? vA2 : 0;
        int vB2 = vB + 2 * nwav; vB2 = (vB2 < V) ? vB2 : 0;
        f32x4 aA2 = x4[(size_t)vA2 * 128 + lane];
        f32x4 bA2 = x4[(size_t)vA2 * 128 + 64 + lane];
        f32x4 aB2 = x4[(size_t)vB2 * 128 + lane];
        f32x4 bB2 = x4[(size_t)vB2 * 128 + 64 + lane];

        // Two independent chains — scheduler interleaves them.
        process_row(aA, bA, vA);
        process_row(aB, bB, vB);

        vA = vA2; vB = vB2;
        aA = aA2; bA = bA2; aB = aB2; bB = bB2;
    }
}

extern "C" void kernel_launch(void* const* d_in, const int* in_sizes, int n_in,
                              void* d_out, int out_size, void* d_ws, size_t ws_size,
                              hipStream_t stream) {
    const float* x = (const float*)d_in[0];
    const float* W = (const float*)d_in[1];
    float* out = (float*)d_out;
    const int V = in_sizes[0] / 512;  // C*D = 512 floats per row

    const int block = 256;
    const int grid  = 2048;  // 8192 waves; 16 rows/wave = 8 pair-iterations
    ipf_kernel<<<grid, block, 0, stream>>>(x, W, out, V);
}

// Round 7
// 95.551 us; speedup vs baseline: 1.0222x; 1.0021x over previous
//
#include <hip/hip_runtime.h>

// InnerProductFeatures: V=131072, C=64, D=8
//   xr[v,d,c] = x[v, d*64 + c]
//   s[v,k]    = sum_{d,c} xr[v,d,c] * W[c,k,d]     (W flat: c*64 + k*8 + d)
//   xOx[v,i]  = sum_k s[v,k] * xr[v,k,i]
//   out       = tanh(xOx)   shape (V, 64) fp32
//
// R7 = DIAGNOSTIC ROUND. Exact R3 kernel (92.2us best), ONLY change:
// grid 2048 -> 512 (2 blocks/CU, 8 waves/CU, half the resident waves).
// Purpose: (a) kernel becomes slower than the harness's ~150us fill
// dispatches so it finally appears in the rocprof top-5 WITH counters
// (FETCH_SIZE / WRITE_SIZE / VALUBusy / OccupancyPercent); (b) discriminates:
//   H1 queuing-bound (BW ~ waves):  dur ~185us, hbm ~1.65 TB/s
//   H2 per-CU pipe cap:             dur ~92-115us, hbm ~3.3 TB/s
//   H3 over-fetch:                  FETCH_SIZE >> 295e3 KB
// Math identical to R3 (verified absmax 4e-3).

typedef float f32x4 __attribute__((ext_vector_type(4)));

__device__ __forceinline__ float fast_tanh(float x) {
    float e = __expf(2.0f * x);
    return 1.0f - 2.0f / (e + 1.0f);
}

// fold16(a,b): even 16-rows get a[l]+a[l^16]; odd rows get b[l]+b[l^16].
__device__ __forceinline__ float fold16(float a, float b, int lane) {
    float x   = (lane & 16) ? a : b;
    float sh  = __shfl_xor(x, 16, 64);
    float own = (lane & 16) ? b : a;
    return own + sh;
}

// fold32(a,b): lanes<32 get a[l]+a[l^32]; lanes>=32 get b[l]+b[l^32].
__device__ __forceinline__ float fold32(float a, float b, int lane) {
    float x   = (lane & 32) ? a : b;
    float sh  = __shfl_xor(x, 32, 64);
    float own = (lane & 32) ? b : a;
    return own + sh;
}

// v + dpp(v): 0xB1 quad xor1, 0x4E quad xor2, 0x141 row_half_mirror (xor4),
// 0x140 row_mirror (xor8).
template <int CTRL>
__device__ __forceinline__ float dpp_add(float v) {
    int i = __builtin_bit_cast(int, v);
    int p = __builtin_amdgcn_update_dpp(i, i, CTRL, 0xF, 0xF, false);
    return v + __builtin_bit_cast(float, p);
}

// Full within-16-lane sum (row-uniform result). VALU-only.
__device__ __forceinline__ float row16_sum(float v) {
    v = dpp_add<0xB1>(v);
    v = dpp_add<0x4E>(v);
    v = dpp_add<0x141>(v);
    v = dpp_add<0x140>(v);
    return v;
}

__global__ __launch_bounds__(256, 4)
void ipf_kernel(const float* __restrict__ x, const float* __restrict__ W,
                float* __restrict__ out, int V) {
    const int tid  = blockIdx.x * blockDim.x + threadIdx.x;
    const int lane = threadIdx.x & 63;
    const int wave = tid >> 6;
    const int nwav = (gridDim.x * blockDim.x) >> 6;

    const int d0 = lane >> 4;         // 0..3
    const int c0 = (lane & 15) << 2;  // 0,4,...,60

    // W fragments in registers: Wa[j][k] = W[c0+j, k, d0], Wb = at d0+4.
    float Wa[4][8], Wb[4][8];
#pragma unroll
    for (int j = 0; j < 4; ++j) {
        const float* wp = W + (size_t)(c0 + j) * 64 + d0;
#pragma unroll
        for (int k = 0; k < 8; ++k) {
            Wa[j][k] = wp[k * 8];
            Wb[j][k] = wp[k * 8 + 4];
        }
    }

    const f32x4* __restrict__ x4 = reinterpret_cast<const f32x4*>(x);

    int v = wave;
    if (v >= V) return;
    f32x4 a = x4[(size_t)v * 128 + lane];
    f32x4 b = x4[(size_t)v * 128 + 64 + lane];

    while (true) {
        const int vn = v + nwav;
        const bool more = (vn < V);
        f32x4 an = a, bn = b;
        if (more) {  // prefetch next row
            an = x4[(size_t)vn * 128 + lane];
            bn = x4[(size_t)vn * 128 + 64 + lane];
        }

        const float xa[4] = {a.x, a.y, a.z, a.w};
        const float xb[4] = {b.x, b.y, b.z, b.w};

        // Stage 1 partials: p[k] = sum_j xa[j]*Wa[j][k] + xb[j]*Wb[j][k]
        float p[8];
#pragma unroll
        for (int k = 0; k < 8; ++k) {
            float acc = 0.0f;
#pragma unroll
            for (int j = 0; j < 4; ++j) {
                acc = fmaf(xa[j], Wa[j][k], acc);
                acc = fmaf(xb[j], Wb[j][k], acc);
            }
            p[k] = acc;
        }

        // Within-row sums (DPP, VALU pipe): row-uniform R_r[k].
#pragma unroll
        for (int k = 0; k < 8; ++k) p[k] = row16_sum(p[k]);

        // Cross-row folds (6 shfl): u = s[d0], w = s[d0+4].
        float t0 = fold16(p[0], p[1], lane);
        float t1 = fold16(p[2], p[3], lane);
        float t2 = fold16(p[4], p[5], lane);
        float t3 = fold16(p[6], p[7], lane);
        float u  = fold32(t0, t1, lane);
        float w  = fold32(t2, t3, lane);

        // Stage 2: contribution to column c0+j from rows d0 and d0+4.
        float q0 = fmaf(u, xa[0], w * xb[0]);
        float q1 = fmaf(u, xa[1], w * xb[1]);
        float q2 = fmaf(u, xa[2], w * xb[2]);
        float q3 = fmaf(u, xa[3], w * xb[3]);

        // Reduce q over the 4 d0-groups (3 shfl); one column per lane.
        float A = fold16(q0, q1, lane);
        float B = fold16(q2, q3, lane);
        float r = fold32(A, B, lane);

        const int col = ((lane & 15) << 2) + d0;
        out[(size_t)v * 64 + col] = fast_tanh(r);

        if (!more) break;
        v = vn; a = an; b = bn;
    }
}

extern "C" void kernel_launch(void* const* d_in, const int* in_sizes, int n_in,
                              void* d_out, int out_size, void* d_ws, size_t ws_size,
                              hipStream_t stream) {
    const float* x = (const float*)d_in[0];
    const float* W = (const float*)d_in[1];
    float* out = (float*)d_out;
    const int V = in_sizes[0] / 512;  // C*D = 512 floats per row

    const int block = 256;
    const int grid  = 512;  // DIAGNOSTIC: 2 blocks/CU (R3 used 2048)
    ipf_kernel<<<grid, block, 0, stream>>>(x, W, out, V);
}